// Round 1
// baseline (923.934 us; speedup 1.0000x reference)
//
#include <hip/hip_runtime.h>

typedef unsigned short u16;
typedef unsigned int u32;
typedef __attribute__((ext_vector_type(4))) float f32x4;
typedef __attribute__((ext_vector_type(8))) __bf16 bf16x8;
typedef __attribute__((ext_vector_type(4))) _Float16 f16x4;
typedef __attribute__((ext_vector_type(4))) u16 u16x4;
typedef __attribute__((ext_vector_type(4))) u32 u32x4;

#define D_ 1024
#define S_ 2048
#define B_ 4
#define H_ 16
#define HD_ 64
#define M_ 8192
#define LDP 72
#define QSCALE 0.18033688011112042591f /* 0.125 * log2(e) */

__device__ __forceinline__ u16 f2bf(float f) {
  u32 u = __float_as_uint(f);
  u += 0x7fffu + ((u >> 16) & 1u);
  return (u16)(u >> 16);
}

// ---------------- cast x (fp32 -> bf16) ----------------
__global__ __launch_bounds__(256) void cast_x_kernel(const float* __restrict__ x,
                                                     u16* __restrict__ xb) {
  int i = (blockIdx.x * 256 + threadIdx.x) * 4;
  f32x4 v = *(const f32x4*)(x + i);
  u16x4 o = {f2bf(v[0]), f2bf(v[1]), f2bf(v[2]), f2bf(v[3])};
  *(u16x4*)(xb + i) = o;
}

// ---------------- transpose+cast weights: Wt[n][k] = bf16(W[k][n]) ----------------
__global__ __launch_bounds__(256) void wtrans_kernel(const float* __restrict__ Wq, const float* __restrict__ Wk,
                                                     const float* __restrict__ Wv, const float* __restrict__ Wo,
                                                     u16* __restrict__ Wqt, u16* __restrict__ Wkt,
                                                     u16* __restrict__ Wvt, u16* __restrict__ Wot) {
  __shared__ float lds[64][65];
  const float* W = blockIdx.z == 0 ? Wq : blockIdx.z == 1 ? Wk : blockIdx.z == 2 ? Wv : Wo;
  u16* Wt       = blockIdx.z == 0 ? Wqt : blockIdx.z == 1 ? Wkt : blockIdx.z == 2 ? Wvt : Wot;
  int k0 = blockIdx.x * 64, n0 = blockIdx.y * 64;
  int tr = threadIdx.x >> 6, tc = threadIdx.x & 63;
#pragma unroll
  for (int i = 0; i < 16; ++i)
    lds[tr + i * 4][tc] = W[(size_t)(k0 + tr + i * 4) * D_ + n0 + tc];
  __syncthreads();
#pragma unroll
  for (int i = 0; i < 16; ++i)
    Wt[(size_t)(n0 + tr + i * 4) * D_ + k0 + tc] = f2bf(lds[tc][tr + i * 4]);
}

// ---------------- shared 128x128 GEMM mainloop (A row-major, Bt = B^T row-major) ----------------
__device__ __forceinline__ void gemm_main(const u16* __restrict__ A, const u16* __restrict__ Bt,
                                          u16* As, u16* Bs, int row0, int col0, f32x4 acc[4][4]) {
  const int tid = threadIdx.x;
  const int lane = tid & 63, wave = tid >> 6;
  const int wr = wave >> 1, wc = wave & 1;
  const int l15 = lane & 15, lg = lane >> 4;
#pragma unroll 1
  for (int k0 = 0; k0 < D_; k0 += 64) {
    __syncthreads();
#pragma unroll
    for (int it = 0; it < 4; ++it) {
      int idx = it * 256 + tid;
      int r = idx >> 3, c = (idx & 7) << 3;
      *(u32x4*)(As + r * LDP + c) = *(const u32x4*)(A + (size_t)(row0 + r) * D_ + k0 + c);
      *(u32x4*)(Bs + r * LDP + c) = *(const u32x4*)(Bt + (size_t)(col0 + r) * D_ + k0 + c);
    }
    __syncthreads();
#pragma unroll
    for (int kk = 0; kk < 64; kk += 32) {
      bf16x8 af[4], bf[4];
#pragma unroll
      for (int m = 0; m < 4; ++m)
        af[m] = *(const bf16x8*)(As + (wr * 64 + m * 16 + l15) * LDP + kk + lg * 8);
#pragma unroll
      for (int n = 0; n < 4; ++n)
        bf[n] = *(const bf16x8*)(Bs + (wc * 64 + n * 16 + l15) * LDP + kk + lg * 8);
#pragma unroll
      for (int m = 0; m < 4; ++m)
#pragma unroll
        for (int n = 0; n < 4; ++n)
          acc[m][n] = __builtin_amdgcn_mfma_f32_16x16x32_bf16(af[m], bf[n], acc[m][n], 0, 0, 0);
    }
  }
}

// ---------------- QKV projection GEMM; z=0 -> Q(scaled bf16), z=1 -> K(bf16), z=2 -> V(f16, transposed) ----------------
__global__ __launch_bounds__(256) void qkv_gemm_kernel(const u16* __restrict__ xb,
                                                       const u16* __restrict__ Wqt, const u16* __restrict__ Wkt,
                                                       const u16* __restrict__ Wvt,
                                                       u16* __restrict__ Qb, u16* __restrict__ Kb,
                                                       _Float16* __restrict__ Vt) {
  __shared__ u16 As[128 * LDP];
  __shared__ u16 Bs[128 * LDP];
  int mode = blockIdx.z;
  const u16* Bt = mode == 0 ? Wqt : mode == 1 ? Wkt : Wvt;
  f32x4 acc[4][4] = {};
  int row0 = blockIdx.y * 128, col0 = blockIdx.x * 128;
  gemm_main(xb, Bt, As, Bs, row0, col0, acc);
  int lane = threadIdx.x & 63, wave = threadIdx.x >> 6;
  int wr = wave >> 1, wc = wave & 1, l15 = lane & 15, lg = lane >> 4;
  int rbase = row0 + wr * 64 + lg * 4, cbase = col0 + wc * 64 + l15;
  if (mode == 2) {
#pragma unroll
    for (int m = 0; m < 4; ++m) {
      int row = rbase + m * 16;
      int b = row >> 11, s = row & (S_ - 1);
#pragma unroll
      for (int n = 0; n < 4; ++n) {
        int col = cbase + n * 16;
        int h = col >> 6, hd = col & 63;
        f16x4 vv = {(_Float16)acc[m][n][0], (_Float16)acc[m][n][1],
                    (_Float16)acc[m][n][2], (_Float16)acc[m][n][3]};
        *(f16x4*)(Vt + ((size_t)((b << 4) + h) * HD_ + hd) * S_ + s) = vv;
      }
    }
  } else {
    u16* dst = mode == 0 ? Qb : Kb;
    float scl = mode == 0 ? QSCALE : 1.0f;
#pragma unroll
    for (int m = 0; m < 4; ++m)
#pragma unroll
      for (int n = 0; n < 4; ++n) {
        int col = cbase + n * 16;
#pragma unroll
        for (int r = 0; r < 4; ++r) {
          int row = rbase + m * 16 + r;
          dst[(size_t)row * D_ + col] = f2bf(acc[m][n][r] * scl);
        }
      }
  }
}

// ---------------- fused causal flash attention ----------------
// 1 wave = 16 q rows. S^T = mfma(K_frag, Q_frag): lane owns q = lane&15, kv = (lane>>4)*4+reg.
// That layout IS the B-fragment of mfma_f32_16x16x16f16, so PV needs no cross-lane movement.
__global__ __launch_bounds__(256) void attn_kernel(const u16* __restrict__ Qb, const u16* __restrict__ Kb,
                                                   const _Float16* __restrict__ Vt, u16* __restrict__ attnb) {
  int wave = threadIdx.x >> 6, lane = threadIdx.x & 63;
  int qg = blockIdx.x * 4 + wave;  // 16-row q group, 0..127
  int bh = blockIdx.y;
  int b = bh >> 4, h = bh & 15;
  int q0 = qg << 4;
  int l15 = lane & 15, lg = lane >> 4;

  const u16* Qrow = Qb + (size_t)(b * S_ + q0 + l15) * D_ + h * HD_;
  bf16x8 qf0 = *(const bf16x8*)(Qrow + lg * 8);
  bf16x8 qf1 = *(const bf16x8*)(Qrow + 32 + lg * 8);

  float m = -1e30f, lsum = 0.f;
  f32x4 o[4] = {};
  const _Float16* Vbase = Vt + (size_t)(bh * HD_ + l15) * S_ + lg * 4;

  for (int t = 0; t <= qg; ++t) {
    int kv0 = t << 4;
    const u16* Krow = Kb + (size_t)(b * S_ + kv0 + l15) * D_ + h * HD_;
    bf16x8 kf0 = *(const bf16x8*)(Krow + lg * 8);
    bf16x8 kf1 = *(const bf16x8*)(Krow + 32 + lg * 8);
    f32x4 s4 = {0.f, 0.f, 0.f, 0.f};
    s4 = __builtin_amdgcn_mfma_f32_16x16x32_bf16(kf0, qf0, s4, 0, 0, 0);
    s4 = __builtin_amdgcn_mfma_f32_16x16x32_bf16(kf1, qf1, s4, 0, 0, 0);
    if (t == qg) {  // diagonal tile: mask kv > q
#pragma unroll
      for (int j = 0; j < 4; ++j)
        if (lg * 4 + j > l15) s4[j] = -1e30f;
    }
    float tmax = fmaxf(fmaxf(s4[0], s4[1]), fmaxf(s4[2], s4[3]));
    tmax = fmaxf(tmax, __shfl_xor(tmax, 16));
    tmax = fmaxf(tmax, __shfl_xor(tmax, 32));
    bool grow = tmax > m;
    if (__any(grow)) {
      float alpha = grow ? exp2f(m - tmax) : 1.0f;
      if (grow) m = tmax;
      lsum *= alpha;
#pragma unroll
      for (int hf = 0; hf < 4; ++hf) o[hf] *= alpha;
    }
    float p0 = exp2f(s4[0] - m), p1 = exp2f(s4[1] - m);
    float p2 = exp2f(s4[2] - m), p3 = exp2f(s4[3] - m);
    float ps = p0 + p1 + p2 + p3;
    ps += __shfl_xor(ps, 16);
    ps += __shfl_xor(ps, 32);
    lsum += ps;
    f16x4 pb = {(_Float16)p0, (_Float16)p1, (_Float16)p2, (_Float16)p3};
    const _Float16* Vp = Vbase + kv0;
#pragma unroll
    for (int hf = 0; hf < 4; ++hf) {
      f16x4 vf = *(const f16x4*)(Vp + (size_t)hf * 16 * S_);
      o[hf] = __builtin_amdgcn_mfma_f32_16x16x16f16(vf, pb, o[hf], 0, 0, 0);
    }
  }
  float inv = 1.0f / lsum;
  u16* Orow = attnb + (size_t)(b * S_ + q0 + l15) * D_ + h * HD_ + lg * 4;
#pragma unroll
  for (int hf = 0; hf < 4; ++hf) {
    u16x4 ov = {f2bf(o[hf][0] * inv), f2bf(o[hf][1] * inv),
                f2bf(o[hf][2] * inv), f2bf(o[hf][3] * inv)};
    *(u16x4*)(Orow + hf * 16) = ov;
  }
}

// ---------------- output projection GEMM (fp32 out + bias) ----------------
__global__ __launch_bounds__(256) void out_gemm_kernel(const u16* __restrict__ attnb, const u16* __restrict__ Wot,
                                                       const float* __restrict__ bo, float* __restrict__ outp) {
  __shared__ u16 As[128 * LDP];
  __shared__ u16 Bs[128 * LDP];
  f32x4 acc[4][4] = {};
  int row0 = blockIdx.y * 128, col0 = blockIdx.x * 128;
  gemm_main(attnb, Wot, As, Bs, row0, col0, acc);
  int lane = threadIdx.x & 63, wave = threadIdx.x >> 6;
  int wr = wave >> 1, wc = wave & 1, l15 = lane & 15, lg = lane >> 4;
  int rbase = row0 + wr * 64 + lg * 4, cbase = col0 + wc * 64 + l15;
#pragma unroll
  for (int n = 0; n < 4; ++n) {
    float bn = bo[cbase + n * 16];
#pragma unroll
    for (int m = 0; m < 4; ++m)
#pragma unroll
      for (int r = 0; r < 4; ++r)
        outp[(size_t)(rbase + m * 16 + r) * D_ + cbase + n * 16] = acc[m][n][r] + bn;
  }
}

extern "C" void kernel_launch(void* const* d_in, const int* in_sizes, int n_in,
                              void* d_out, int out_size, void* d_ws, size_t ws_size,
                              hipStream_t stream) {
  const float* x  = (const float*)d_in[0];
  const float* Wq = (const float*)d_in[1];
  const float* Wk = (const float*)d_in[2];
  const float* Wv = (const float*)d_in[3];
  const float* Wo = (const float*)d_in[4];
  const float* bo = (const float*)d_in[5];
  float* outp = (float*)d_out;

  char* ws = (char*)d_ws;
  u16* xb        = (u16*)(ws);                          // 16 MiB
  u16* Wqt       = (u16*)(ws + ((size_t)16 << 20));     // 2 MiB
  u16* Wkt       = (u16*)(ws + ((size_t)18 << 20));
  u16* Wvt       = (u16*)(ws + ((size_t)20 << 20));
  u16* Wot       = (u16*)(ws + ((size_t)22 << 20));
  u16* Qb        = (u16*)(ws + ((size_t)24 << 20));     // 16 MiB
  u16* Kb        = (u16*)(ws + ((size_t)40 << 20));     // 16 MiB
  _Float16* Vt   = (_Float16*)(ws + ((size_t)56 << 20));// 16 MiB
  u16* attnb     = (u16*)(ws + ((size_t)72 << 20));     // 16 MiB

  cast_x_kernel<<<dim3(M_ * D_ / (256 * 4)), dim3(256), 0, stream>>>(x, xb);
  wtrans_kernel<<<dim3(16, 16, 4), dim3(256), 0, stream>>>(Wq, Wk, Wv, Wo, Wqt, Wkt, Wvt, Wot);
  qkv_gemm_kernel<<<dim3(D_ / 128, M_ / 128, 3), dim3(256), 0, stream>>>(xb, Wqt, Wkt, Wvt, Qb, Kb, Vt);
  attn_kernel<<<dim3(S_ / 64, B_ * H_), dim3(256), 0, stream>>>(Qb, Kb, Vt, attnb);
  out_gemm_kernel<<<dim3(D_ / 128, M_ / 128), dim3(256), 0, stream>>>(attnb, Wot, bo, outp);
}

// Round 3
// 261.722 us; speedup vs baseline: 3.5302x; 3.5302x over previous
//
#include <hip/hip_runtime.h>

typedef unsigned short u16;
typedef unsigned int u32;
typedef __attribute__((ext_vector_type(4))) float f32x4;
typedef __attribute__((ext_vector_type(8))) __bf16 bf16x8;
typedef __attribute__((ext_vector_type(4))) _Float16 f16x4;
typedef __attribute__((ext_vector_type(4))) u16 u16x4;
typedef __attribute__((ext_vector_type(4))) u32 u32x4;

#define D_ 1024
#define S_ 2048
#define B_ 4
#define H_ 16
#define HD_ 64
#define M_ 8192
#define LDP 72
#define QSCALE 0.18033688011112042591f /* 0.125 * log2(e) */

__device__ __forceinline__ u16 f2bf(float f) {
  u32 u = __float_as_uint(f);
  u += 0x7fffu + ((u >> 16) & 1u);
  return (u16)(u >> 16);
}

// ---------------- cast x (fp32 -> bf16) ----------------
__global__ __launch_bounds__(256) void cast_x_kernel(const float* __restrict__ x,
                                                     u16* __restrict__ xb) {
  int i = (blockIdx.x * 256 + threadIdx.x) * 4;
  f32x4 v = *(const f32x4*)(x + i);
  u16x4 o = {f2bf(v[0]), f2bf(v[1]), f2bf(v[2]), f2bf(v[3])};
  *(u16x4*)(xb + i) = o;
}

// ---------------- transpose+cast weights: Wt[n][k] = bf16(W[k][n]) ----------------
__global__ __launch_bounds__(256) void wtrans_kernel(const float* __restrict__ Wq, const float* __restrict__ Wk,
                                                     const float* __restrict__ Wv, const float* __restrict__ Wo,
                                                     u16* __restrict__ Wqt, u16* __restrict__ Wkt,
                                                     u16* __restrict__ Wvt, u16* __restrict__ Wot) {
  __shared__ float lds[64][65];
  const float* W = blockIdx.z == 0 ? Wq : blockIdx.z == 1 ? Wk : blockIdx.z == 2 ? Wv : Wo;
  u16* Wt       = blockIdx.z == 0 ? Wqt : blockIdx.z == 1 ? Wkt : blockIdx.z == 2 ? Wvt : Wot;
  int k0 = blockIdx.x * 64, n0 = blockIdx.y * 64;
  int tr = threadIdx.x >> 6, tc = threadIdx.x & 63;
#pragma unroll
  for (int i = 0; i < 16; ++i)
    lds[tr + i * 4][tc] = W[(size_t)(k0 + tr + i * 4) * D_ + n0 + tc];
  __syncthreads();
#pragma unroll
  for (int i = 0; i < 16; ++i)
    Wt[(size_t)(n0 + tr + i * 4) * D_ + k0 + tc] = f2bf(lds[tc][tr + i * 4]);
}

// ---------------- shared 128x128 GEMM mainloop (A row-major, Bt = B^T row-major) ----------------
__device__ __forceinline__ void gemm_main(const u16* __restrict__ A, const u16* __restrict__ Bt,
                                          u16* As, u16* Bs, int row0, int col0, f32x4 acc[4][4]) {
  const int tid = threadIdx.x;
  const int lane = tid & 63, wave = tid >> 6;
  const int wr = wave >> 1, wc = wave & 1;
  const int l15 = lane & 15, lg = lane >> 4;
#pragma unroll 1
  for (int k0 = 0; k0 < D_; k0 += 64) {
    __syncthreads();
#pragma unroll
    for (int it = 0; it < 4; ++it) {
      int idx = it * 256 + tid;
      int r = idx >> 3, c = (idx & 7) << 3;
      *(u32x4*)(As + r * LDP + c) = *(const u32x4*)(A + (size_t)(row0 + r) * D_ + k0 + c);
      *(u32x4*)(Bs + r * LDP + c) = *(const u32x4*)(Bt + (size_t)(col0 + r) * D_ + k0 + c);
    }
    __syncthreads();
#pragma unroll
    for (int kk = 0; kk < 64; kk += 32) {
      bf16x8 af[4], bf[4];
#pragma unroll
      for (int m = 0; m < 4; ++m)
        af[m] = *(const bf16x8*)(As + (wr * 64 + m * 16 + l15) * LDP + kk + lg * 8);
#pragma unroll
      for (int n = 0; n < 4; ++n)
        bf[n] = *(const bf16x8*)(Bs + (wc * 64 + n * 16 + l15) * LDP + kk + lg * 8);
#pragma unroll
      for (int m = 0; m < 4; ++m)
#pragma unroll
        for (int n = 0; n < 4; ++n)
          acc[m][n] = __builtin_amdgcn_mfma_f32_16x16x32_bf16(af[m], bf[n], acc[m][n], 0, 0, 0);
    }
  }
}

// ---------------- QKV projection GEMM; z=0 -> Q(scaled bf16), z=1 -> K(bf16), z=2 -> V(f16, transposed) ----------------
__global__ __launch_bounds__(256) void qkv_gemm_kernel(const u16* __restrict__ xb,
                                                       const u16* __restrict__ Wqt, const u16* __restrict__ Wkt,
                                                       const u16* __restrict__ Wvt,
                                                       u16* __restrict__ Qb, u16* __restrict__ Kb,
                                                       _Float16* __restrict__ Vt) {
  __shared__ u16 As[128 * LDP];
  __shared__ u16 Bs[128 * LDP];
  int mode = blockIdx.z;
  const u16* Bt = mode == 0 ? Wqt : mode == 1 ? Wkt : Wvt;
  f32x4 acc[4][4] = {};
  int row0 = blockIdx.y * 128, col0 = blockIdx.x * 128;
  gemm_main(xb, Bt, As, Bs, row0, col0, acc);
  int lane = threadIdx.x & 63, wave = threadIdx.x >> 6;
  int wr = wave >> 1, wc = wave & 1, l15 = lane & 15, lg = lane >> 4;
  int rbase = row0 + wr * 64 + lg * 4, cbase = col0 + wc * 64 + l15;
  if (mode == 2) {
#pragma unroll
    for (int m = 0; m < 4; ++m) {
      int row = rbase + m * 16;
      int b = row >> 11, s = row & (S_ - 1);
#pragma unroll
      for (int n = 0; n < 4; ++n) {
        int col = cbase + n * 16;
        int h = col >> 6, hd = col & 63;
        f16x4 vv = {(_Float16)acc[m][n][0], (_Float16)acc[m][n][1],
                    (_Float16)acc[m][n][2], (_Float16)acc[m][n][3]};
        *(f16x4*)(Vt + ((size_t)((b << 4) + h) * HD_ + hd) * S_ + s) = vv;
      }
    }
  } else {
    u16* dst = mode == 0 ? Qb : Kb;
    float scl = mode == 0 ? QSCALE : 1.0f;
#pragma unroll
    for (int m = 0; m < 4; ++m)
#pragma unroll
      for (int n = 0; n < 4; ++n) {
        int col = cbase + n * 16;
#pragma unroll
        for (int r = 0; r < 4; ++r) {
          int row = rbase + m * 16 + r;
          dst[(size_t)row * D_ + col] = f2bf(acc[m][n][r] * scl);
        }
      }
  }
}

// ---------------- fused causal flash attention, v2 ----------------
// Block = 4 waves, one (b,h); wave w owns q rows [q0b + w*16, +16).
// KV tile = 64, staged in LDS (shared by the 4 waves), double-buffered,
// async-stage order: issue loads(t+1) -> compute(t) -> ds_write(t+1).
// Swapped QK^T: s = mfma(K,Q) => lane owns q = lane&15, kv = j*16 + (lane>>4)*4 + r.
// That layout IS the B-fragment of mfma_f32_16x16x16f16, so PV needs no cross-lane movement.
__global__ __launch_bounds__(256) void attn_kernel(const u16* __restrict__ Qb, const u16* __restrict__ Kb,
                                                   const _Float16* __restrict__ Vt, u16* __restrict__ attnb) {
  __shared__ u16 Ks[2][64][LDP];       // [kv][hd], padded row 144B
  __shared__ _Float16 Vs[2][HD_][LDP]; // [hd][kv], padded row 144B
  const int tid = threadIdx.x;
  const int wave = tid >> 6, lane = tid & 63;
  const int l15 = lane & 15, lg = lane >> 4;
  const int bh = blockIdx.y, b = bh >> 4, h = bh & 15;
  const int qblk = blockIdx.x;          // q rows [qblk*64, +64)
  const int q0b = qblk * 64;
  const int ntiles = qblk + 1;

  const u16* Qrow = Qb + (size_t)(b * S_ + q0b + wave * 16 + l15) * D_ + h * HD_;
  bf16x8 qf0 = *(const bf16x8*)(Qrow + lg * 8);
  bf16x8 qf1 = *(const bf16x8*)(Qrow + 32 + lg * 8);

  // staging geometry: thread t covers rows {t>>3, 32+(t>>3)}, 16B chunk (t&7)*16 bytes
  const int srow = tid >> 3;
  const int scol = (tid & 7) * 8;  // in u16/f16 elems (16B)
  const u16* Kg = Kb + (size_t)(b * S_) * D_ + h * HD_;
  const _Float16* Vg = Vt + (size_t)bh * HD_ * S_;

  float m = -1e30f, lsum = 0.f;
  f32x4 o[4] = {};
  u32x4 kreg0, kreg1, vreg0, vreg1;

  // prologue: tile 0 -> regs -> LDS buf0
  kreg0 = *(const u32x4*)(Kg + (size_t)(srow) * D_ + scol);
  kreg1 = *(const u32x4*)(Kg + (size_t)(32 + srow) * D_ + scol);
  vreg0 = *(const u32x4*)(Vg + (size_t)srow * S_ + scol);
  vreg1 = *(const u32x4*)(Vg + (size_t)(32 + srow) * S_ + scol);
  *(u32x4*)(&Ks[0][srow][scol]) = kreg0;
  *(u32x4*)(&Ks[0][32 + srow][scol]) = kreg1;
  *(u32x4*)(&Vs[0][srow][scol]) = vreg0;
  *(u32x4*)(&Vs[0][32 + srow][scol]) = vreg1;

#pragma unroll 1
  for (int t = 0; t < ntiles; ++t) {
    const int cur = t & 1;
    __syncthreads();  // tile t visible in buf[cur]
    // issue global loads for tile t+1 (overlap with compute below)
    if (t + 1 < ntiles) {
      int kv0 = (t + 1) * 64;
      kreg0 = *(const u32x4*)(Kg + (size_t)(kv0 + srow) * D_ + scol);
      kreg1 = *(const u32x4*)(Kg + (size_t)(kv0 + 32 + srow) * D_ + scol);
      vreg0 = *(const u32x4*)(Vg + (size_t)srow * S_ + kv0 + scol);
      vreg1 = *(const u32x4*)(Vg + (size_t)(32 + srow) * S_ + kv0 + scol);
    }
    // ---- QK^T: 4 subtiles of 16 kv ----
    f32x4 s[4];
    __builtin_amdgcn_s_setprio(1);
#pragma unroll
    for (int j = 0; j < 4; ++j) {
      bf16x8 kf0 = *(const bf16x8*)(&Ks[cur][j * 16 + l15][lg * 8]);
      bf16x8 kf1 = *(const bf16x8*)(&Ks[cur][j * 16 + l15][32 + lg * 8]);
      f32x4 z = {0.f, 0.f, 0.f, 0.f};
      z = __builtin_amdgcn_mfma_f32_16x16x32_bf16(kf0, qf0, z, 0, 0, 0);
      z = __builtin_amdgcn_mfma_f32_16x16x32_bf16(kf1, qf1, z, 0, 0, 0);
      s[j] = z;
    }
    __builtin_amdgcn_s_setprio(0);
    // ---- mask (diagonal tile only) ----
    if (t == ntiles - 1) {
      int qr = wave * 16 + l15;
#pragma unroll
      for (int j = 0; j < 4; ++j)
#pragma unroll
        for (int r = 0; r < 4; ++r)
          if (j * 16 + lg * 4 + r > qr) s[j][r] = -1e30f;
    }
    // ---- online softmax (one row-reduce per 64 kv) ----
    float t0 = fmaxf(fmaxf(s[0][0], s[0][1]), fmaxf(s[0][2], s[0][3]));
    float t1 = fmaxf(fmaxf(s[1][0], s[1][1]), fmaxf(s[1][2], s[1][3]));
    float t2 = fmaxf(fmaxf(s[2][0], s[2][1]), fmaxf(s[2][2], s[2][3]));
    float t3 = fmaxf(fmaxf(s[3][0], s[3][1]), fmaxf(s[3][2], s[3][3]));
    float tmax = fmaxf(fmaxf(t0, t1), fmaxf(t2, t3));
    tmax = fmaxf(tmax, __shfl_xor(tmax, 16));
    tmax = fmaxf(tmax, __shfl_xor(tmax, 32));
    if (!__all(tmax - m <= 8.f)) {  // defer-max (T13)
      float nm = fmaxf(m, tmax);
      float alpha = exp2f(m - nm);
      m = nm;
      lsum *= alpha;
#pragma unroll
      for (int hf = 0; hf < 4; ++hf) o[hf] *= alpha;
    }
    f16x4 pb[4];
#pragma unroll
    for (int j = 0; j < 4; ++j) {
      float p0 = exp2f(s[j][0] - m), p1 = exp2f(s[j][1] - m);
      float p2 = exp2f(s[j][2] - m), p3 = exp2f(s[j][3] - m);
      lsum += (p0 + p1) + (p2 + p3);
      pb[j] = (f16x4){(_Float16)p0, (_Float16)p1, (_Float16)p2, (_Float16)p3};
    }
    // ---- PV: o[hf] += V^T[hf] * P ----
    __builtin_amdgcn_s_setprio(1);
#pragma unroll
    for (int j = 0; j < 4; ++j) {
#pragma unroll
      for (int hf = 0; hf < 4; ++hf) {
        f16x4 vf = *(const f16x4*)(&Vs[cur][hf * 16 + l15][j * 16 + lg * 4]);
        o[hf] = __builtin_amdgcn_mfma_f32_16x16x16f16(vf, pb[j], o[hf], 0, 0, 0);
      }
    }
    __builtin_amdgcn_s_setprio(0);
    // ---- write tile t+1 into the other buffer (safe: all waves passed top barrier) ----
    if (t + 1 < ntiles) {
      const int nxt = cur ^ 1;
      *(u32x4*)(&Ks[nxt][srow][scol]) = kreg0;
      *(u32x4*)(&Ks[nxt][32 + srow][scol]) = kreg1;
      *(u32x4*)(&Vs[nxt][srow][scol]) = vreg0;
      *(u32x4*)(&Vs[nxt][32 + srow][scol]) = vreg1;
    }
  }
  // ---- epilogue: reduce lsum across the 4 lane-groups, normalize, store ----
  lsum += __shfl_xor(lsum, 16);
  lsum += __shfl_xor(lsum, 32);
  float inv = 1.0f / lsum;
  u16* Orow = attnb + (size_t)(b * S_ + q0b + wave * 16 + l15) * D_ + h * HD_ + lg * 4;
#pragma unroll
  for (int hf = 0; hf < 4; ++hf) {
    u16x4 ov = {f2bf(o[hf][0] * inv), f2bf(o[hf][1] * inv),
                f2bf(o[hf][2] * inv), f2bf(o[hf][3] * inv)};
    *(u16x4*)(Orow + hf * 16) = ov;
  }
}

// ---------------- output projection GEMM (fp32 out + bias) ----------------
__global__ __launch_bounds__(256) void out_gemm_kernel(const u16* __restrict__ attnb, const u16* __restrict__ Wot,
                                                       const float* __restrict__ bo, float* __restrict__ outp) {
  __shared__ u16 As[128 * LDP];
  __shared__ u16 Bs[128 * LDP];
  f32x4 acc[4][4] = {};
  int row0 = blockIdx.y * 128, col0 = blockIdx.x * 128;
  gemm_main(attnb, Wot, As, Bs, row0, col0, acc);
  int lane = threadIdx.x & 63, wave = threadIdx.x >> 6;
  int wr = wave >> 1, wc = wave & 1, l15 = lane & 15, lg = lane >> 4;
  int rbase = row0 + wr * 64 + lg * 4, cbase = col0 + wc * 64 + l15;
#pragma unroll
  for (int n = 0; n < 4; ++n) {
    float bn = bo[cbase + n * 16];
#pragma unroll
    for (int m = 0; m < 4; ++m)
#pragma unroll
      for (int r = 0; r < 4; ++r)
        outp[(size_t)(rbase + m * 16 + r) * D_ + cbase + n * 16] = acc[m][n][r] + bn;
  }
}

extern "C" void kernel_launch(void* const* d_in, const int* in_sizes, int n_in,
                              void* d_out, int out_size, void* d_ws, size_t ws_size,
                              hipStream_t stream) {
  const float* x  = (const float*)d_in[0];
  const float* Wq = (const float*)d_in[1];
  const float* Wk = (const float*)d_in[2];
  const float* Wv = (const float*)d_in[3];
  const float* Wo = (const float*)d_in[4];
  const float* bo = (const float*)d_in[5];
  float* outp = (float*)d_out;

  char* ws = (char*)d_ws;
  u16* xb        = (u16*)(ws);                          // 16 MiB
  u16* Wqt       = (u16*)(ws + ((size_t)16 << 20));     // 2 MiB
  u16* Wkt       = (u16*)(ws + ((size_t)18 << 20));
  u16* Wvt       = (u16*)(ws + ((size_t)20 << 20));
  u16* Wot       = (u16*)(ws + ((size_t)22 << 20));
  u16* Qb        = (u16*)(ws + ((size_t)24 << 20));     // 16 MiB
  u16* Kb        = (u16*)(ws + ((size_t)40 << 20));     // 16 MiB
  _Float16* Vt   = (_Float16*)(ws + ((size_t)56 << 20));// 16 MiB
  u16* attnb     = (u16*)(ws + ((size_t)72 << 20));     // 16 MiB

  cast_x_kernel<<<dim3(M_ * D_ / (256 * 4)), dim3(256), 0, stream>>>(x, xb);
  wtrans_kernel<<<dim3(16, 16, 4), dim3(256), 0, stream>>>(Wq, Wk, Wv, Wo, Wqt, Wkt, Wvt, Wot);
  qkv_gemm_kernel<<<dim3(D_ / 128, M_ / 128, 3), dim3(256), 0, stream>>>(xb, Wqt, Wkt, Wvt, Qb, Kb, Vt);
  attn_kernel<<<dim3(S_ / 64, B_ * H_), dim3(256), 0, stream>>>(Qb, Kb, Vt, attnb);
  out_gemm_kernel<<<dim3(D_ / 128, M_ / 128), dim3(256), 0, stream>>>(attnb, Wot, bo, outp);
}